// Round 1
// baseline (23.396 us; speedup 1.0000x reference)
//
#include <hip/hip_runtime.h>
#include <math.h>

// Problem constants (fixed by the reference setup)
constexpr int J = 26;
constexpr int BATCH = 65536;
constexpr int THREADS = 256;
constexpr int GROUPS_PER_BLOCK = THREADS / 32;          // 8 rows per block-pass
constexpr int NBLOCKS = 2048;
constexpr int ROWS_PER_ITER = NBLOCKS * GROUPS_PER_BLOCK; // 16384
constexpr int NITER = BATCH / ROWS_PER_ITER;              // 4
constexpr float INV_COUNT = 1.0f; // unused; we divide explicitly

// Sum across a 32-lane group (lanes with j>=26 must contribute 0)
__device__ inline float grpsum32(float v) {
    v += __shfl_xor(v, 1, 32);
    v += __shfl_xor(v, 2, 32);
    v += __shfl_xor(v, 4, 32);
    v += __shfl_xor(v, 8, 32);
    v += __shfl_xor(v, 16, 32);
    return v;
}

__global__ __launch_bounds__(THREADS) void mv_loss_partial(
    const float* __restrict__ pj,    // [B, J, 3] pred_joints
    const float* __restrict__ pt,    // [B, 3]    pred_trans
    const float* __restrict__ gj,    // [B, J, 4] gt_joints (xyz + conf)
    const float* __restrict__ gtr,   // [B, 3]    gt_trans
    const float* __restrict__ focal, // [B]
    float* __restrict__ partials)    // [NBLOCKS]
{
    const int tid = threadIdx.x;
    const int grp = tid >> 5;
    const int lj  = tid & 31;
    const bool act = (lj < J);

    float acc = 0.f;

    for (int it = 0; it < NITER; ++it) {
        const int b = (it * NBLOCKS + blockIdx.x) * GROUPS_PER_BLOCK + grp;

        // ---- loads (predicated for lanes >= J) ----
        float px = 0.f, py = 0.f, pz = 0.f, gx = 0.f, gy = 0.f, gz = 0.f;
        if (act) {
            const float* p = pj + (size_t)b * (3 * J) + 3 * lj;
            px = p[0]; py = p[1]; pz = p[2];
            const float4 g = *reinterpret_cast<const float4*>(gj + (size_t)b * (4 * J) + 4 * lj);
            gx = g.x; gy = g.y; gz = g.z;
        }
        const float f = focal[b];
        px += pt[3 * b + 0]; py += pt[3 * b + 1]; pz += pt[3 * b + 2];
        gx += gtr[3 * b + 0]; gy += gtr[3 * b + 1]; gz += gtr[3 * b + 2];

        // ---- c1 = mean(gt, axis=joints) with z zeroed ----
        const float c1x = grpsum32(act ? gx : 0.f) / 26.f;
        const float c1y = grpsum32(act ? gy : 0.f) / 26.f;
        // c1z = 0

        // Rotations about x (f32 constants: cos90 = 6.1e-17, sin180 = 1.2e-16
        // are >= 9 orders below ulp of every operand -> exact swap/neg forms):
        // R90   : (x,y,z) -> ( x, -z,  y)
        // -R90  : (x,y,z) -> (-x,  z, -y)
        // R180  : (x,y,z) -> ( x, -y, -z)
        // RM90  : (x,y,z) -> ( x,  z, -y)
        // -RM90 : (x,y,z) -> (-x, -z,  y)

        float vx, vy, vz;

        // view 1: R90 about c1
        vx = px - c1x; vy = py - c1y; vz = pz;
        const float p1x = vx + c1x, p1y = -vz + c1y, p1z = vy;
        vx = gx - c1x; vy = gy - c1y; vz = gz;
        const float g1x = vx + c1x, g1y = -vz + c1y, g1z = vy;

        // view 2: -R90 applied to view-1 points, about c1
        vx = p1x - c1x; vy = p1y - c1y; vz = p1z;
        const float p2x = -vx + c1x, p2y = vz + c1y, p2z = -vy;
        vx = g1x - c1x; vy = g1y - c1y; vz = g1z;
        const float g2x = -vx + c1x, g2y = vz + c1y, g2z = -vy;

        // view 3: R180 about c1
        vx = px - c1x; vy = py - c1y; vz = pz;
        const float p3x = vx + c1x, p3y = -vy + c1y, p3z = -vz;
        vx = gx - c1x; vy = gy - c1y; vz = gz;
        const float g3x = vx + c1x, g3y = -vy + c1y, g3z = -vz;

        // ---- c2 = mean(g1, axis=joints) with z zeroed ----
        const float c2x = grpsum32(act ? g1x : 0.f) / 26.f;
        const float c2y = grpsum32(act ? g1y : 0.f) / 26.f;

        // view 4: RM90 applied to view-1 points, about c2
        vx = p1x - c2x; vy = p1y - c2y; vz = p1z;
        const float p4x = vx + c2x, p4y = vz + c2y, p4z = -vy;
        vx = g1x - c2x; vy = g1y - c2y; vz = g1z;
        const float g4x = vx + c2x, g4y = vz + c2y, g4z = -vy;

        // view 5: -RM90 applied to view-3 points, about c2
        vx = p3x - c2x; vy = p3y - c2y; vz = p3z;
        const float p5x = -vx + c2x, p5y = -vz + c2y, p5z = vy;
        vx = g3x - c2x; vy = g3y - c2y; vz = g3z;
        const float g5x = -vx + c2x, g5y = -vz + c2y, g5z = vy;

        // ---- projection + squared diff, accumulate ----
        auto pacc = [&](float pX, float pY, float pZ,
                        float gX, float gY, float gZ) {
            const float rp = __builtin_amdgcn_rcpf(pZ);
            const float rg = __builtin_amdgcn_rcpf(gZ);
            const float dx = (f * pX) * rp - (f * gX) * rg;
            const float dy = (f * pY) * rp - (f * gY) * rg;
            const float t = dx * dx + dy * dy;
            acc += act ? t : 0.f;   // select (not multiply) so inactive inf/NaN can't leak
        };
        pacc(p1x, p1y, p1z, g1x, g1y, g1z);
        pacc(p2x, p2y, p2z, g2x, g2y, g2z);
        pacc(p3x, p3y, p3z, g3x, g3y, g3z);
        pacc(p4x, p4y, p4z, g4x, g4y, g4z);
        pacc(p5x, p5y, p5z, g5x, g5y, g5z);
    }

    // ---- block reduction (deterministic) ----
    for (int off = 32; off > 0; off >>= 1)
        acc += __shfl_xor(acc, off, 64);
    __shared__ float wsum[THREADS / 64];
    if ((tid & 63) == 0) wsum[tid >> 6] = acc;
    __syncthreads();
    if (tid == 0)
        partials[blockIdx.x] = (wsum[0] + wsum[1]) + (wsum[2] + wsum[3]);
}

__global__ __launch_bounds__(256) void mv_loss_final(
    const float* __restrict__ partials, float* __restrict__ out)
{
    float s = 0.f;
    for (int i = threadIdx.x; i < NBLOCKS; i += 256) s += partials[i];
    for (int off = 32; off > 0; off >>= 1)
        s += __shfl_xor(s, off, 64);
    __shared__ float wsum[4];
    if ((threadIdx.x & 63) == 0) wsum[threadIdx.x >> 6] = s;
    __syncthreads();
    if (threadIdx.x == 0) {
        float total = (wsum[0] + wsum[1]) + (wsum[2] + wsum[3]);
        float loss = total / (float)(BATCH * J * 2);  // sum of 5 means == total/(B*J*2)
        if (loss > 1500.f || isnan(loss)) loss = 0.f;
        out[0] = loss * 1000.f;
    }
}

extern "C" void kernel_launch(void* const* d_in, const int* in_sizes, int n_in,
                              void* d_out, int out_size, void* d_ws, size_t ws_size,
                              hipStream_t stream) {
    const float* pred_joints = (const float*)d_in[0];
    const float* pred_trans  = (const float*)d_in[1];
    const float* gt_joints   = (const float*)d_in[2];
    const float* gt_trans    = (const float*)d_in[3];
    // d_in[4]=valid, d_in[5]=img_h, d_in[6]=img_w are unused by the reference
    const float* focal       = (const float*)d_in[7];

    float* partials = (float*)d_ws;          // 2048 floats = 8 KB
    float* out = (float*)d_out;

    mv_loss_partial<<<NBLOCKS, THREADS, 0, stream>>>(
        pred_joints, pred_trans, gt_joints, gt_trans, focal, partials);
    mv_loss_final<<<1, 256, 0, stream>>>(partials, out);
}